// Round 1
// baseline (2577.274 us; speedup 1.0000x reference)
//
#include <hip/hip_runtime.h>
#include <cstdint>
#include <cstddef>

#define TT 1024
#define BB 1024
#define NOBS 18
#define NACT 5
#define NIN 23
#define HH 64
#define G4 256
#define ZZ 32
#define RPB 2   // batch rows per block

__device__ __forceinline__ float sigm(float x) {
    return 1.f / (1.f + __expf(-x));
}

// overflow-safe tanh: exp(2|x|) >= 1, inf -> result 1
__device__ __forceinline__ float tanh_f(float x) {
    float ax = fabsf(x);
    float e  = __expf(2.f * ax);
    float r  = 1.f - 2.f / (e + 1.f);
    return copysignf(r, x);
}

__global__ __launch_bounds__(256, 2)
void wm_kernel(const float* __restrict__ obs, const float* __restrict__ act,
               const float* __restrict__ h0,  const float* __restrict__ c0,
               const float* __restrict__ W_enc, const float* __restrict__ b_enc,
               const float* __restrict__ W_ih,  const float* __restrict__ W_hh,
               const float* __restrict__ b_ih,  const float* __restrict__ b_hh,
               const float* __restrict__ W_pred, const float* __restrict__ b_pred,
               const float* __restrict__ W_z,    const float* __restrict__ b_z,
               float* __restrict__ out_pred, float* __restrict__ out_z,
               float* __restrict__ out_h,    float* __restrict__ out_c)
{
    __shared__ __attribute__((aligned(16))) float wencT[NIN * HH];   // [k][u] transposed
    __shared__ __attribute__((aligned(16))) float xs[RPB * HH];
    __shared__ __attribute__((aligned(16))) float hs[RPB * HH];
    __shared__ __attribute__((aligned(16))) float gbuf[RPB * G4];

    const int tid = threadIdx.x;
    const int bid = blockIdx.x;
    const int u   = tid & 63;
    const int r   = (tid >> 6) & 1;       // row index within block (both halves)
    const bool lo = (tid < 128);          // waves 0,1: encoder + cell update
    const int rowg = bid * RPB + r;       // global batch row this thread serves

    // ---- one-time init ----
    for (int i = tid; i < NIN * HH; i += 256) {
        int k = i >> 6, uu = i & 63;
        wencT[i] = W_enc[uu * NIN + k];
    }

    // gate weights for row j = tid, in registers
    float wih[HH], whh[HH];
    {
        const float4* pih = (const float4*)(W_ih + tid * HH);
        const float4* phh = (const float4*)(W_hh + tid * HH);
#pragma unroll
        for (int kk = 0; kk < 16; ++kk) {
            float4 a = pih[kk];
            wih[4*kk+0] = a.x; wih[4*kk+1] = a.y; wih[4*kk+2] = a.z; wih[4*kk+3] = a.w;
            float4 b = phh[kk];
            whh[4*kk+0] = b.x; whh[4*kk+1] = b.y; whh[4*kk+2] = b.z; whh[4*kk+3] = b.w;
        }
    }
    const float bias = b_ih[tid] + b_hh[tid];
    const float benc = b_enc[u];

    // epilogue weights (used by waves 2,3): u<18 -> pred row u; 18<=u<50 -> z row u-18
    float wout[HH];
    float bout = 0.f;
    {
        const float* src;
        if (u < 18)      { src = W_pred + u * HH;        bout = b_pred[u]; }
        else if (u < 50) { src = W_z + (u - 18) * HH;    bout = b_z[u - 18]; }
        else             { src = W_pred; }   // dummy, never used
        const float4* p4 = (const float4*)src;
#pragma unroll
        for (int kk = 0; kk < 16; ++kk) {
            float4 a = p4[kk];
            wout[4*kk+0] = a.x; wout[4*kk+1] = a.y; wout[4*kk+2] = a.z; wout[4*kk+3] = a.w;
        }
    }

    // state init
    float c = 0.f;
    if (lo) {
        hs[r * HH + u] = h0[(size_t)rowg * HH + u];
        c = c0[(size_t)rowg * HH + u];
    }

    const float* obs_row = obs + (size_t)rowg * TT * NOBS;
    const float* act_row = act + (size_t)rowg * TT * NACT;
    float* outp_row = out_pred + (size_t)rowg * TT * NOBS;
    float* outz_row = out_z    + (size_t)rowg * TT * ZZ;

    __syncthreads();

    for (int t = 0; t < TT; ++t) {
        // ---- encoder (waves 0,1): x = relu(W_enc @ [obs;act] + b_enc) ----
        if (lo) {
            const float* op = obs_row + t * NOBS;
            const float* ap = act_row + t * NACT;
            float acc = benc;
#pragma unroll
            for (int k = 0; k < NOBS; ++k) acc = fmaf(op[k], wencT[k * HH + u], acc);
#pragma unroll
            for (int k = 0; k < NACT; ++k) acc = fmaf(ap[k], wencT[(NOBS + k) * HH + u], acc);
            xs[r * HH + u] = fmaxf(acc, 0.f);
        }
        __syncthreads();   // B1: xs ready; prev-step hs ready; gbuf consumed

        // ---- gates (all 256 threads): gate row j = tid for both batch rows ----
        {
            float a0 = bias, b0 = 0.f, a1 = bias, b1 = 0.f;
            const float4* x4 = (const float4*)xs;
            const float4* h4 = (const float4*)hs;
#pragma unroll
            for (int kk = 0; kk < 16; ++kk) {
                float4 xv0 = x4[kk];
                float4 hv0 = h4[kk];
                float4 xv1 = x4[16 + kk];
                float4 hv1 = h4[16 + kk];
                a0 = fmaf(wih[4*kk+0], xv0.x, a0);
                a0 = fmaf(wih[4*kk+1], xv0.y, a0);
                a0 = fmaf(wih[4*kk+2], xv0.z, a0);
                a0 = fmaf(wih[4*kk+3], xv0.w, a0);
                b0 = fmaf(whh[4*kk+0], hv0.x, b0);
                b0 = fmaf(whh[4*kk+1], hv0.y, b0);
                b0 = fmaf(whh[4*kk+2], hv0.z, b0);
                b0 = fmaf(whh[4*kk+3], hv0.w, b0);
                a1 = fmaf(wih[4*kk+0], xv1.x, a1);
                a1 = fmaf(wih[4*kk+1], xv1.y, a1);
                a1 = fmaf(wih[4*kk+2], xv1.z, a1);
                a1 = fmaf(wih[4*kk+3], xv1.w, a1);
                b1 = fmaf(whh[4*kk+0], hv1.x, b1);
                b1 = fmaf(whh[4*kk+1], hv1.y, b1);
                b1 = fmaf(whh[4*kk+2], hv1.z, b1);
                b1 = fmaf(whh[4*kk+3], hv1.w, b1);
            }
            gbuf[tid]      = a0 + b0;
            gbuf[G4 + tid] = a1 + b1;
        }
        __syncthreads();   // B2: gbuf ready

        // ---- cell update (waves 0,1) ----
        if (lo) {
            float gi = gbuf[r * G4 + u];
            float gf = gbuf[r * G4 + 64 + u];
            float gg = gbuf[r * G4 + 128 + u];
            float go = gbuf[r * G4 + 192 + u];
            c = sigm(gf) * c + sigm(gi) * tanh_f(gg);
            float ht = sigm(go) * tanh_f(c);
            hs[r * HH + u] = ht;
            if (t == TT - 1) {
                out_h[(size_t)rowg * HH + u] = ht;
                out_c[(size_t)rowg * HH + u] = c;
            }
        }
        __syncthreads();   // B3: new hs ready for epilogue

        // ---- epilogue (waves 2,3): pred = sigmoid(W_pred@h+b), z = W_z@h+b ----
        if (!lo && u < 50) {
            float acc = bout;
            const float4* h4 = (const float4*)(hs + r * HH);
#pragma unroll
            for (int kk = 0; kk < 16; ++kk) {
                float4 hv = h4[kk];
                acc = fmaf(wout[4*kk+0], hv.x, acc);
                acc = fmaf(wout[4*kk+1], hv.y, acc);
                acc = fmaf(wout[4*kk+2], hv.z, acc);
                acc = fmaf(wout[4*kk+3], hv.w, acc);
            }
            if (u < 18) outp_row[t * NOBS + u] = sigm(acc);
            else        outz_row[t * ZZ + (u - 18)] = acc;
        }
        // no barrier needed here: next-iter B1/B2 separate all hazards
    }
}

extern "C" void kernel_launch(void* const* d_in, const int* in_sizes, int n_in,
                              void* d_out, int out_size, void* d_ws, size_t ws_size,
                              hipStream_t stream)
{
    const float* obs    = (const float*)d_in[0];
    const float* act    = (const float*)d_in[1];
    const float* h0     = (const float*)d_in[2];
    const float* c0     = (const float*)d_in[3];
    const float* W_enc  = (const float*)d_in[4];
    const float* b_enc  = (const float*)d_in[5];
    const float* W_ih   = (const float*)d_in[6];
    const float* W_hh   = (const float*)d_in[7];
    const float* b_ih   = (const float*)d_in[8];
    const float* b_hh   = (const float*)d_in[9];
    const float* W_pred = (const float*)d_in[10];
    const float* b_pred = (const float*)d_in[11];
    const float* W_z    = (const float*)d_in[12];
    const float* b_z    = (const float*)d_in[13];

    float* out      = (float*)d_out;
    float* out_pred = out;
    float* out_z    = out_pred + (size_t)BB * TT * NOBS;
    float* out_h    = out_z    + (size_t)BB * TT * ZZ;
    float* out_c    = out_h    + (size_t)BB * HH;

    wm_kernel<<<dim3(BB / RPB), dim3(256), 0, stream>>>(
        obs, act, h0, c0, W_enc, b_enc, W_ih, W_hh, b_ih, b_hh,
        W_pred, b_pred, W_z, b_z, out_pred, out_z, out_h, out_c);
}

// Round 2
// 2021.324 us; speedup vs baseline: 1.2750x; 1.2750x over previous
//
#include <hip/hip_runtime.h>
#include <cstdint>
#include <cstddef>

#define TT 1024
#define BB 1024
#define NOBS 18
#define NACT 5
#define HH 64
#define ZZ 32

typedef __attribute__((ext_vector_type(8))) short short8;
typedef __attribute__((ext_vector_type(4))) float f32x4;

union Frag { short8 v; unsigned short u[8]; };

__device__ __forceinline__ unsigned short f2bf(float f) {
    unsigned u = __float_as_uint(f);
    return (unsigned short)((u + 0x7FFFu + ((u >> 16) & 1u)) >> 16);
}
__device__ __forceinline__ float bf2f(unsigned short h) {
    return __uint_as_float(((unsigned)h) << 16);
}
__device__ __forceinline__ unsigned pk2(float a, float b) {
    return (unsigned)f2bf(a) | ((unsigned)f2bf(b) << 16);
}
__device__ __forceinline__ float sigm(float x) {
    return __builtin_amdgcn_rcpf(1.f + __expf(-x));
}
// self-saturating tanh: x->+inf => e=inf, rcp=0 => 1 ; x->-inf => e=0 => -1
__device__ __forceinline__ float tanh_(float x) {
    float e = __expf(2.f * x);
    return 1.f - 2.f * __builtin_amdgcn_rcpf(e + 1.f);
}

#define XG_SHORTS ((size_t)64 * 1024 * 4 * 64 * 16)         // 268,435,456
#define HSEQ_SHORTS ((size_t)BB * TT * HH)                  // 67,108,864
#define WS_NEEDED ((XG_SHORTS + HSEQ_SHORTS) * 2)           // 671,088,640 B

// ============================ PASS 1 =====================================
// grid: 64 rowblocks x 128 t-chunks (8 t per block). 256 threads = 4 waves.
// enc: x = relu(W_enc @ [obs;act] + b_enc)   (M=64, K=32 pad, N=16 rows)
// xg  = W_ih @ x + (b_ih + b_hh)             (M=256, K=64,  N=16 rows)
// xg stored in C-frag order: [rb][t][w][lane][16 bf16]
#define P1T 8
__global__ __launch_bounds__(256, 2)
void pass1_kernel(const float* __restrict__ obs, const float* __restrict__ act,
                  const float* __restrict__ W_enc, const float* __restrict__ b_enc,
                  const float* __restrict__ W_ih,
                  const float* __restrict__ b_ih, const float* __restrict__ b_hh,
                  unsigned short* __restrict__ xg)
{
    __shared__ __attribute__((aligned(16))) unsigned short in_s[P1T * 16 * 40]; // [t][r][f] pad 40
    __shared__ __attribute__((aligned(16))) unsigned short x_s[P1T * 16 * 72];  // [t][r][u] pad 72

    const int tid = threadIdx.x;
    const int w = tid >> 6, L = tid & 63, q = L >> 4, n = L & 15;
    const int rb = blockIdx.x & 63;
    const int t0 = (blockIdx.x >> 6) * P1T;

    // ---- A-frags: encoder (4 M-tiles, K=32 with zero pad >=23) ----
    Frag aenc[4];
#pragma unroll
    for (int tm = 0; tm < 4; ++tm) {
        int m = 16 * tm + n;
#pragma unroll
        for (int j = 0; j < 8; ++j) {
            int k = 8 * q + j;
            aenc[tm].u[j] = (k < 23) ? f2bf(W_enc[m * 23 + k]) : (unsigned short)0;
        }
    }
    // ---- A-frags: gate weights W_ih, wave w owns M-tiles {w,4+w,8+w,12+w} ----
    Frag ag[4][2];
#pragma unroll
    for (int tm = 0; tm < 4; ++tm) {
        int m = 16 * (w + 4 * tm) + n;
#pragma unroll
        for (int kt = 0; kt < 2; ++kt)
#pragma unroll
            for (int j = 0; j < 8; ++j)
                ag[tm][kt].u[j] = f2bf(W_ih[m * 64 + 32 * kt + 8 * q + j]);
    }
    // per-lane bias values (C layout: m = 16*tile + 4q + jj)
    float benc_r[4][4], bg[4][4];
#pragma unroll
    for (int tm = 0; tm < 4; ++tm)
#pragma unroll
        for (int jj = 0; jj < 4; ++jj) {
            benc_r[tm][jj] = b_enc[16 * tm + 4 * q + jj];
            int m = 16 * (w + 4 * tm) + 4 * q + jj;
            bg[tm][jj] = b_ih[m] + b_hh[m];
        }

    // ---- stage inputs -> LDS (bf16, zero-padded feats 23..39) ----
    for (int i = tid; i < P1T * 16 * NOBS; i += 256) {
        int r = i / (P1T * NOBS), rem = i % (P1T * NOBS), t = rem / NOBS, f = rem % NOBS;
        float v = obs[(((size_t)(rb * 16 + r)) * TT + t0 + t) * NOBS + f];
        in_s[(t * 16 + r) * 40 + f] = f2bf(v);
    }
    for (int i = tid; i < P1T * 16 * NACT; i += 256) {
        int r = i / (P1T * NACT), rem = i % (P1T * NACT), t = rem / NACT, f = rem % NACT;
        float v = act[(((size_t)(rb * 16 + r)) * TT + t0 + t) * NACT + f];
        in_s[(t * 16 + r) * 40 + NOBS + f] = f2bf(v);
    }
    for (int i = tid; i < P1T * 16 * 17; i += 256) {
        int r = i / (P1T * 17), rem = i % (P1T * 17), t = rem / 17, f = 23 + rem % 17;
        in_s[(t * 16 + r) * 40 + f] = 0;
    }
    __syncthreads();

    // ---- encoder: wave w handles t = 2w, 2w+1 ----
#pragma unroll
    for (int tt = 0; tt < 2; ++tt) {
        int t = 2 * w + tt;
        short8 bin = *(const short8*)&in_s[(t * 16 + n) * 40 + 8 * q];
        f32x4 xa[4];
#pragma unroll
        for (int tm = 0; tm < 4; ++tm) {
            xa[tm] = (f32x4){benc_r[tm][0], benc_r[tm][1], benc_r[tm][2], benc_r[tm][3]};
            xa[tm] = __builtin_amdgcn_mfma_f32_16x16x32_bf16(aenc[tm].v, bin, xa[tm], 0, 0, 0);
        }
        // relu + cvt + write x_s  (lane writes units 16tm+4q .. +3 of row n)
#pragma unroll
        for (int tm = 0; tm < 4; ++tm) {
            uint2 xw;
            xw.x = pk2(fmaxf(xa[tm][0], 0.f), fmaxf(xa[tm][1], 0.f));
            xw.y = pk2(fmaxf(xa[tm][2], 0.f), fmaxf(xa[tm][3], 0.f));
            *(uint2*)&x_s[(t * 16 + n) * 72 + 16 * tm + 4 * q] = xw;
        }
    }
    __syncthreads();

    // ---- xg: wave w computes its 4 M-tiles for all 8 t ----
    for (int t = 0; t < P1T; ++t) {
        short8 bx0 = *(const short8*)&x_s[(t * 16 + n) * 72 + 8 * q];
        short8 bx1 = *(const short8*)&x_s[(t * 16 + n) * 72 + 32 + 8 * q];
        f32x4 acc[4];
#pragma unroll
        for (int tm = 0; tm < 4; ++tm) {
            acc[tm] = (f32x4){bg[tm][0], bg[tm][1], bg[tm][2], bg[tm][3]};
            acc[tm] = __builtin_amdgcn_mfma_f32_16x16x32_bf16(ag[tm][0].v, bx0, acc[tm], 0, 0, 0);
            acc[tm] = __builtin_amdgcn_mfma_f32_16x16x32_bf16(ag[tm][1].v, bx1, acc[tm], 0, 0, 0);
        }
        size_t off = ((((size_t)rb * TT + t0 + t) * 4 + w) * 64 + L) * 16;
        uint4 lo, hi;
        lo.x = pk2(acc[0][0], acc[0][1]); lo.y = pk2(acc[0][2], acc[0][3]);
        lo.z = pk2(acc[1][0], acc[1][1]); lo.w = pk2(acc[1][2], acc[1][3]);
        hi.x = pk2(acc[2][0], acc[2][1]); hi.y = pk2(acc[2][2], acc[2][3]);
        hi.z = pk2(acc[3][0], acc[3][1]); hi.w = pk2(acc[3][2], acc[3][3]);
        *(uint4*)&xg[off] = lo;
        *(uint4*)&xg[off + 8] = hi;
    }
}

// ============================ PASS 2 =====================================
// 64 blocks (16 rows each) x 4 waves. Wave w owns gate tiles {w,4+w,8+w,12+w}
// => lane holds i,f,g,o for 4 units x 1 row: shuffle-free cell update.
__global__ __launch_bounds__(256, 1)
void pass2_kernel(const unsigned short* __restrict__ xg,
                  const float* __restrict__ h0, const float* __restrict__ c0,
                  const float* __restrict__ W_hh,
                  unsigned short* __restrict__ hseq,
                  float* __restrict__ out_h, float* __restrict__ out_c)
{
    __shared__ __attribute__((aligned(16))) unsigned short h_s[2][16 * 72];

    const int tid = threadIdx.x;
    const int w = tid >> 6, L = tid & 63, q = L >> 4, n = L & 15;
    const int rb = blockIdx.x;

    // W_hh A-frags (constant across steps)
    Frag ahh[4][2];
#pragma unroll
    for (int tm = 0; tm < 4; ++tm) {
        int m = 16 * (w + 4 * tm) + n;
#pragma unroll
        for (int kt = 0; kt < 2; ++kt)
#pragma unroll
            for (int j = 0; j < 8; ++j)
                ahh[tm][kt].u[j] = f2bf(W_hh[m * 64 + 32 * kt + 8 * q + j]);
    }
    // c state: lane owns units u = 16w + 4q + jj of row n
    float c[4];
    {
        const float4* cp = (const float4*)&c0[((size_t)(rb * 16 + n)) * 64 + 16 * w + 4 * q];
        float4 cv = *cp;
        c[0] = cv.x; c[1] = cv.y; c[2] = cv.z; c[3] = cv.w;
    }
    // h init (cooperative): thread -> row tid>>4, units (tid&15)*4..+3
    {
        int r = tid >> 4, u0 = (tid & 15) * 4;
        float4 hv = *(const float4*)&h0[((size_t)(rb * 16 + r)) * 64 + u0];
        uint2 hw; hw.x = pk2(hv.x, hv.y); hw.y = pk2(hv.z, hv.w);
        *(uint2*)&h_s[0][r * 72 + u0] = hw;
    }
    __syncthreads();

    const unsigned short* xp = xg + (((size_t)rb * TT * 4 + w) * 64 + L) * 16;
    // distance-2 prefetch
    uint4 xlo[2], xhi[2];
    xlo[0] = *(const uint4*)xp;            xhi[0] = *(const uint4*)(xp + 8);
    xlo[1] = *(const uint4*)(xp + 4096);   xhi[1] = *(const uint4*)(xp + 4096 + 8);

    float hout[4] = {0.f, 0.f, 0.f, 0.f};

    for (int t = 0; t < TT; ++t) {
        const int p = t & 1;
        short8 hb0 = *(const short8*)&h_s[p][n * 72 + 8 * q];
        short8 hb1 = *(const short8*)&h_s[p][n * 72 + 32 + 8 * q];

        // acc init = xg (bias already folded in pass1)
        uint4 lo = xlo[p], hi = xhi[p];
        f32x4 acc[4];
        acc[0] = (f32x4){bf2f(lo.x & 0xffff), bf2f(lo.x >> 16), bf2f(lo.y & 0xffff), bf2f(lo.y >> 16)};
        acc[1] = (f32x4){bf2f(lo.z & 0xffff), bf2f(lo.z >> 16), bf2f(lo.w & 0xffff), bf2f(lo.w >> 16)};
        acc[2] = (f32x4){bf2f(hi.x & 0xffff), bf2f(hi.x >> 16), bf2f(hi.y & 0xffff), bf2f(hi.y >> 16)};
        acc[3] = (f32x4){bf2f(hi.z & 0xffff), bf2f(hi.z >> 16), bf2f(hi.w & 0xffff), bf2f(hi.w >> 16)};
        // prefetch t+2 into this slot
        if (t + 2 < TT) {
            xlo[p] = *(const uint4*)(xp + (size_t)(t + 2) * 4096);
            xhi[p] = *(const uint4*)(xp + (size_t)(t + 2) * 4096 + 8);
        }
#pragma unroll
        for (int tm = 0; tm < 4; ++tm) {
            acc[tm] = __builtin_amdgcn_mfma_f32_16x16x32_bf16(ahh[tm][0].v, hb0, acc[tm], 0, 0, 0);
            acc[tm] = __builtin_amdgcn_mfma_f32_16x16x32_bf16(ahh[tm][1].v, hb1, acc[tm], 0, 0, 0);
        }
        // activations: acc[0]=i, acc[1]=f, acc[2]=g, acc[3]=o
#pragma unroll
        for (int jj = 0; jj < 4; ++jj) {
            float cn = sigm(acc[1][jj]) * c[jj] + sigm(acc[0][jj]) * tanh_(acc[2][jj]);
            c[jj] = cn;
            hout[jj] = sigm(acc[3][jj]) * tanh_(cn);
        }
        uint2 hw; hw.x = pk2(hout[0], hout[1]); hw.y = pk2(hout[2], hout[3]);
        *(uint2*)&h_s[1 - p][n * 72 + 16 * w + 4 * q] = hw;
        *(uint2*)&hseq[(((size_t)rb * TT + t) * 16 + n) * 64 + 16 * w + 4 * q] = hw;
        __syncthreads();
    }

    // final state out (fp32)
    {
        size_t o = ((size_t)(rb * 16 + n)) * 64 + 16 * w + 4 * q;
        *(float4*)&out_h[o] = make_float4(hout[0], hout[1], hout[2], hout[3]);
        *(float4*)&out_c[o] = make_float4(c[0], c[1], c[2], c[3]);
    }
}

// ============================ PASS 3 =====================================
// heads: pred = sigmoid(W_pred@h+b) [18], z = W_z@h+b [32]; combined M=64 pad.
// grid: 1024 rows x 4; each block: 4 chunks x (4 waves x 16 t) = 256 t.
__global__ __launch_bounds__(256, 2)
void pass3_kernel(const unsigned short* __restrict__ hseq,
                  const float* __restrict__ W_pred, const float* __restrict__ b_pred,
                  const float* __restrict__ W_z, const float* __restrict__ b_z,
                  float* __restrict__ out_pred, float* __restrict__ out_z)
{
    const int tid = threadIdx.x;
    const int w = tid >> 6, L = tid & 63, q = L >> 4, n = L & 15;
    const int row = blockIdx.x >> 2;
    const int bc = blockIdx.x & 3;
    const int rb = row >> 4, r = row & 15;

    Frag aw[4][2];
    float bo[4][4];
#pragma unroll
    for (int tm = 0; tm < 4; ++tm) {
        int m = 16 * tm + n;
#pragma unroll
        for (int kt = 0; kt < 2; ++kt)
#pragma unroll
            for (int j = 0; j < 8; ++j) {
                int k = 32 * kt + 8 * q + j;
                unsigned short v = 0;
                if (m < 18)      v = f2bf(W_pred[m * 64 + k]);
                else if (m < 50) v = f2bf(W_z[(m - 18) * 64 + k]);
                aw[tm][kt].u[j] = v;
            }
#pragma unroll
        for (int jj = 0; jj < 4; ++jj) {
            int m2 = 16 * tm + 4 * q + jj;
            bo[tm][jj] = (m2 < 18) ? b_pred[m2] : (m2 < 50 ? b_z[m2 - 18] : 0.f);
        }
    }

    for (int it = 0; it < 4; ++it) {
        int t = bc * 256 + it * 64 + w * 16 + n;
        size_t hb = (((size_t)rb * TT + t) * 16 + r) * 64;
        short8 hb0 = *(const short8*)&hseq[hb + 8 * q];
        short8 hb1 = *(const short8*)&hseq[hb + 32 + 8 * q];
        f32x4 acc[4];
#pragma unroll
        for (int tm = 0; tm < 4; ++tm) {
            acc[tm] = (f32x4){bo[tm][0], bo[tm][1], bo[tm][2], bo[tm][3]};
            acc[tm] = __builtin_amdgcn_mfma_f32_16x16x32_bf16(aw[tm][0].v, hb0, acc[tm], 0, 0, 0);
            acc[tm] = __builtin_amdgcn_mfma_f32_16x16x32_bf16(aw[tm][1].v, hb1, acc[tm], 0, 0, 0);
        }
        size_t pbase = ((size_t)row * TT + t) * NOBS;
        size_t zbase = ((size_t)row * TT + t) * ZZ;
#pragma unroll
        for (int tm = 0; tm < 4; ++tm)
#pragma unroll
            for (int jj = 0; jj < 4; ++jj) {
                int m = 16 * tm + 4 * q + jj;
                float v = acc[tm][jj];
                if (m < 18)      out_pred[pbase + m] = sigm(v);
                else if (m < 50) out_z[zbase + m - 18] = v;
            }
    }
}

// ===================== FALLBACK (R1 monolithic kernel) ====================
#define G4 256
#define RPB 2
__device__ __forceinline__ float tanh_safe(float x) {
    float ax = fabsf(x);
    float e = __expf(2.f * ax);
    float r = 1.f - 2.f / (e + 1.f);
    return copysignf(r, x);
}
__global__ __launch_bounds__(256, 2)
void wm_fallback(const float* __restrict__ obs, const float* __restrict__ act,
                 const float* __restrict__ h0, const float* __restrict__ c0,
                 const float* __restrict__ W_enc, const float* __restrict__ b_enc,
                 const float* __restrict__ W_ih, const float* __restrict__ W_hh,
                 const float* __restrict__ b_ih, const float* __restrict__ b_hh,
                 const float* __restrict__ W_pred, const float* __restrict__ b_pred,
                 const float* __restrict__ W_z, const float* __restrict__ b_z,
                 float* __restrict__ out_pred, float* __restrict__ out_z,
                 float* __restrict__ out_h, float* __restrict__ out_c)
{
    __shared__ __attribute__((aligned(16))) float wencT[23 * HH];
    __shared__ __attribute__((aligned(16))) float xs[RPB * HH];
    __shared__ __attribute__((aligned(16))) float hs[RPB * HH];
    __shared__ __attribute__((aligned(16))) float gbuf[RPB * G4];
    const int tid = threadIdx.x, bid = blockIdx.x;
    const int u = tid & 63, r = (tid >> 6) & 1;
    const bool lo = (tid < 128);
    const int rowg = bid * RPB + r;
    for (int i = tid; i < 23 * HH; i += 256) { int k = i >> 6, uu = i & 63; wencT[i] = W_enc[uu * 23 + k]; }
    float wih[HH], whh[HH];
    {
        const float4* pih = (const float4*)(W_ih + tid * HH);
        const float4* phh = (const float4*)(W_hh + tid * HH);
#pragma unroll
        for (int kk = 0; kk < 16; ++kk) {
            float4 a = pih[kk]; wih[4*kk] = a.x; wih[4*kk+1] = a.y; wih[4*kk+2] = a.z; wih[4*kk+3] = a.w;
            float4 b = phh[kk]; whh[4*kk] = b.x; whh[4*kk+1] = b.y; whh[4*kk+2] = b.z; whh[4*kk+3] = b.w;
        }
    }
    const float bias = b_ih[tid] + b_hh[tid];
    const float benc = b_enc[u];
    float wout[HH]; float bout = 0.f;
    {
        const float* src;
        if (u < 18) { src = W_pred + u * HH; bout = b_pred[u]; }
        else if (u < 50) { src = W_z + (u - 18) * HH; bout = b_z[u - 18]; }
        else src = W_pred;
        const float4* p4 = (const float4*)src;
#pragma unroll
        for (int kk = 0; kk < 16; ++kk) { float4 a = p4[kk]; wout[4*kk] = a.x; wout[4*kk+1] = a.y; wout[4*kk+2] = a.z; wout[4*kk+3] = a.w; }
    }
    float c = 0.f;
    if (lo) { hs[r * HH + u] = h0[(size_t)rowg * HH + u]; c = c0[(size_t)rowg * HH + u]; }
    const float* obs_row = obs + (size_t)rowg * TT * NOBS;
    const float* act_row = act + (size_t)rowg * TT * NACT;
    float* outp_row = out_pred + (size_t)rowg * TT * NOBS;
    float* outz_row = out_z + (size_t)rowg * TT * ZZ;
    __syncthreads();
    for (int t = 0; t < TT; ++t) {
        if (lo) {
            const float* op = obs_row + t * NOBS; const float* ap = act_row + t * NACT;
            float a = benc;
#pragma unroll
            for (int k = 0; k < NOBS; ++k) a = fmaf(op[k], wencT[k * HH + u], a);
#pragma unroll
            for (int k = 0; k < NACT; ++k) a = fmaf(ap[k], wencT[(NOBS + k) * HH + u], a);
            xs[r * HH + u] = fmaxf(a, 0.f);
        }
        __syncthreads();
        {
            float a0 = bias, b0 = 0.f, a1 = bias, b1 = 0.f;
            const float4* x4 = (const float4*)xs; const float4* h4 = (const float4*)hs;
#pragma unroll
            for (int kk = 0; kk < 16; ++kk) {
                float4 xv0 = x4[kk], hv0 = h4[kk], xv1 = x4[16 + kk], hv1 = h4[16 + kk];
                a0 = fmaf(wih[4*kk], xv0.x, a0); a0 = fmaf(wih[4*kk+1], xv0.y, a0);
                a0 = fmaf(wih[4*kk+2], xv0.z, a0); a0 = fmaf(wih[4*kk+3], xv0.w, a0);
                b0 = fmaf(whh[4*kk], hv0.x, b0); b0 = fmaf(whh[4*kk+1], hv0.y, b0);
                b0 = fmaf(whh[4*kk+2], hv0.z, b0); b0 = fmaf(whh[4*kk+3], hv0.w, b0);
                a1 = fmaf(wih[4*kk], xv1.x, a1); a1 = fmaf(wih[4*kk+1], xv1.y, a1);
                a1 = fmaf(wih[4*kk+2], xv1.z, a1); a1 = fmaf(wih[4*kk+3], xv1.w, a1);
                b1 = fmaf(whh[4*kk], hv1.x, b1); b1 = fmaf(whh[4*kk+1], hv1.y, b1);
                b1 = fmaf(whh[4*kk+2], hv1.z, b1); b1 = fmaf(whh[4*kk+3], hv1.w, b1);
            }
            gbuf[tid] = a0 + b0; gbuf[G4 + tid] = a1 + b1;
        }
        __syncthreads();
        if (lo) {
            float gi = gbuf[r * G4 + u], gf = gbuf[r * G4 + 64 + u];
            float gg = gbuf[r * G4 + 128 + u], go = gbuf[r * G4 + 192 + u];
            c = sigm(gf) * c + sigm(gi) * tanh_safe(gg);
            float ht = sigm(go) * tanh_safe(c);
            hs[r * HH + u] = ht;
            if (t == TT - 1) { out_h[(size_t)rowg * HH + u] = ht; out_c[(size_t)rowg * HH + u] = c; }
        }
        __syncthreads();
        if (!lo && u < 50) {
            float a = bout;
            const float4* h4 = (const float4*)(hs + r * HH);
#pragma unroll
            for (int kk = 0; kk < 16; ++kk) {
                float4 hv = h4[kk];
                a = fmaf(wout[4*kk], hv.x, a); a = fmaf(wout[4*kk+1], hv.y, a);
                a = fmaf(wout[4*kk+2], hv.z, a); a = fmaf(wout[4*kk+3], hv.w, a);
            }
            if (u < 18) outp_row[t * NOBS + u] = sigm(a);
            else outz_row[t * ZZ + (u - 18)] = a;
        }
    }
}

// ============================ LAUNCH =====================================
extern "C" void kernel_launch(void* const* d_in, const int* in_sizes, int n_in,
                              void* d_out, int out_size, void* d_ws, size_t ws_size,
                              hipStream_t stream)
{
    const float* obs    = (const float*)d_in[0];
    const float* act    = (const float*)d_in[1];
    const float* h0     = (const float*)d_in[2];
    const float* c0     = (const float*)d_in[3];
    const float* W_enc  = (const float*)d_in[4];
    const float* b_enc  = (const float*)d_in[5];
    const float* W_ih   = (const float*)d_in[6];
    const float* W_hh   = (const float*)d_in[7];
    const float* b_ih   = (const float*)d_in[8];
    const float* b_hh   = (const float*)d_in[9];
    const float* W_pred = (const float*)d_in[10];
    const float* b_pred = (const float*)d_in[11];
    const float* W_z    = (const float*)d_in[12];
    const float* b_z    = (const float*)d_in[13];

    float* out      = (float*)d_out;
    float* out_pred = out;
    float* out_z    = out_pred + (size_t)BB * TT * NOBS;
    float* out_h    = out_z + (size_t)BB * TT * ZZ;
    float* out_c    = out_h + (size_t)BB * HH;

    if (ws_size >= WS_NEEDED) {
        unsigned short* xg   = (unsigned short*)d_ws;
        unsigned short* hseq = xg + XG_SHORTS;
        pass1_kernel<<<dim3(64 * 128), dim3(256), 0, stream>>>(
            obs, act, W_enc, b_enc, W_ih, b_ih, b_hh, xg);
        pass2_kernel<<<dim3(64), dim3(256), 0, stream>>>(
            xg, h0, c0, W_hh, hseq, out_h, out_c);
        pass3_kernel<<<dim3(1024 * 4), dim3(256), 0, stream>>>(
            hseq, W_pred, b_pred, W_z, b_z, out_pred, out_z);
    } else {
        wm_fallback<<<dim3(BB / RPB), dim3(256), 0, stream>>>(
            obs, act, h0, c0, W_enc, b_enc, W_ih, W_hh, b_ih, b_hh,
            W_pred, b_pred, W_z, b_z, out_pred, out_z, out_h, out_c);
    }
}

// Round 3
// 1597.668 us; speedup vs baseline: 1.6131x; 1.2652x over previous
//
#include <hip/hip_runtime.h>
#include <cstdint>
#include <cstddef>

#define TT 1024
#define BB 1024
#define NOBS 18
#define NACT 5
#define HH 64
#define ZZ 32

typedef __attribute__((ext_vector_type(8))) short short8;
typedef __attribute__((ext_vector_type(4))) float f32x4;

union Frag { short8 v; unsigned short u[8]; };

__device__ __forceinline__ unsigned short f2bf(float f) {
    unsigned u = __float_as_uint(f);
    return (unsigned short)((u + 0x7FFFu + ((u >> 16) & 1u)) >> 16);
}
__device__ __forceinline__ float bf2f(unsigned short h) {
    return __uint_as_float(((unsigned)h) << 16);
}
__device__ __forceinline__ unsigned pk2(float a, float b) {
    return (unsigned)f2bf(a) | ((unsigned)f2bf(b) << 16);
}
__device__ __forceinline__ float sigm(float x) {
    return __builtin_amdgcn_rcpf(1.f + __expf(-x));
}
// self-saturating tanh: x->+inf => e=inf, rcp=0 => 1 ; x->-inf => e=0 => -1
__device__ __forceinline__ float tanh_(float x) {
    float e = __expf(2.f * x);
    return 1.f - 2.f * __builtin_amdgcn_rcpf(e + 1.f);
}

#define XG_SHORTS ((size_t)64 * 1024 * 4 * 64 * 16)   // 268,435,456 shorts
#define WS_NEEDED (XG_SHORTS * 2)                     // 536,870,912 B

// ============================ PASS 1 =====================================
// grid: 64 rowblocks x 64 t-chunks (16 t per block). 256 threads = 4 waves.
// xg stored in C-frag order: [rb][t][w][lane][16 bf16], bias folded in.
#define P1T 16
__global__ __launch_bounds__(256, 2)
void pass1_kernel(const float* __restrict__ obs, const float* __restrict__ act,
                  const float* __restrict__ W_enc, const float* __restrict__ b_enc,
                  const float* __restrict__ W_ih,
                  const float* __restrict__ b_ih, const float* __restrict__ b_hh,
                  unsigned short* __restrict__ xg)
{
    __shared__ __attribute__((aligned(16))) unsigned short in_s[P1T * 16 * 40]; // [t][r][f] pad 40
    __shared__ __attribute__((aligned(16))) unsigned short x_s[P1T * 16 * 72];  // [t][r][u] pad 72

    const int tid = threadIdx.x;
    const int w = tid >> 6, L = tid & 63, q = L >> 4, n = L & 15;
    const int rb = blockIdx.x & 63;
    const int t0 = (blockIdx.x >> 6) * P1T;

    // ---- A-frags: encoder (4 M-tiles, K=32 with zero pad >=23) ----
    Frag aenc[4];
#pragma unroll
    for (int tm = 0; tm < 4; ++tm) {
        int m = 16 * tm + n;
#pragma unroll
        for (int j = 0; j < 8; ++j) {
            int k = 8 * q + j;
            aenc[tm].u[j] = (k < 23) ? f2bf(W_enc[m * 23 + k]) : (unsigned short)0;
        }
    }
    // ---- A-frags: gate weights W_ih, wave w owns M-tiles {w,4+w,8+w,12+w} ----
    Frag ag[4][2];
#pragma unroll
    for (int tm = 0; tm < 4; ++tm) {
        int m = 16 * (w + 4 * tm) + n;
#pragma unroll
        for (int kt = 0; kt < 2; ++kt)
#pragma unroll
            for (int j = 0; j < 8; ++j)
                ag[tm][kt].u[j] = f2bf(W_ih[m * 64 + 32 * kt + 8 * q + j]);
    }
    float benc_r[4][4], bg[4][4];
#pragma unroll
    for (int tm = 0; tm < 4; ++tm)
#pragma unroll
        for (int jj = 0; jj < 4; ++jj) {
            benc_r[tm][jj] = b_enc[16 * tm + 4 * q + jj];
            int m = 16 * (w + 4 * tm) + 4 * q + jj;
            bg[tm][jj] = b_ih[m] + b_hh[m];
        }

    // ---- stage inputs -> LDS (bf16, zero-padded feats 23..39) ----
    for (int i = tid; i < P1T * 16 * NOBS; i += 256) {
        int r = i / (P1T * NOBS), rem = i % (P1T * NOBS), t = rem / NOBS, f = rem % NOBS;
        float v = obs[(((size_t)(rb * 16 + r)) * TT + t0 + t) * NOBS + f];
        in_s[(t * 16 + r) * 40 + f] = f2bf(v);
    }
    for (int i = tid; i < P1T * 16 * NACT; i += 256) {
        int r = i / (P1T * NACT), rem = i % (P1T * NACT), t = rem / NACT, f = rem % NACT;
        float v = act[(((size_t)(rb * 16 + r)) * TT + t0 + t) * NACT + f];
        in_s[(t * 16 + r) * 40 + NOBS + f] = f2bf(v);
    }
    for (int i = tid; i < P1T * 16 * 17; i += 256) {
        int r = i / (P1T * 17), rem = i % (P1T * 17), t = rem / 17, f = 23 + rem % 17;
        in_s[(t * 16 + r) * 40 + f] = 0;
    }
    __syncthreads();

    // ---- encoder: wave w handles t = 4w .. 4w+3 ----
#pragma unroll
    for (int tt = 0; tt < 4; ++tt) {
        int t = 4 * w + tt;
        short8 bin = *(const short8*)&in_s[(t * 16 + n) * 40 + 8 * q];
        f32x4 xa[4];
#pragma unroll
        for (int tm = 0; tm < 4; ++tm) {
            xa[tm] = (f32x4){benc_r[tm][0], benc_r[tm][1], benc_r[tm][2], benc_r[tm][3]};
            xa[tm] = __builtin_amdgcn_mfma_f32_16x16x32_bf16(aenc[tm].v, bin, xa[tm], 0, 0, 0);
        }
#pragma unroll
        for (int tm = 0; tm < 4; ++tm) {
            uint2 xw;
            xw.x = pk2(fmaxf(xa[tm][0], 0.f), fmaxf(xa[tm][1], 0.f));
            xw.y = pk2(fmaxf(xa[tm][2], 0.f), fmaxf(xa[tm][3], 0.f));
            *(uint2*)&x_s[(t * 16 + n) * 72 + 16 * tm + 4 * q] = xw;
        }
    }
    __syncthreads();

    // ---- xg: wave w computes its 4 M-tiles for all 16 t ----
    for (int t = 0; t < P1T; ++t) {
        short8 bx0 = *(const short8*)&x_s[(t * 16 + n) * 72 + 8 * q];
        short8 bx1 = *(const short8*)&x_s[(t * 16 + n) * 72 + 32 + 8 * q];
        f32x4 acc[4];
#pragma unroll
        for (int tm = 0; tm < 4; ++tm) {
            acc[tm] = (f32x4){bg[tm][0], bg[tm][1], bg[tm][2], bg[tm][3]};
            acc[tm] = __builtin_amdgcn_mfma_f32_16x16x32_bf16(ag[tm][0].v, bx0, acc[tm], 0, 0, 0);
            acc[tm] = __builtin_amdgcn_mfma_f32_16x16x32_bf16(ag[tm][1].v, bx1, acc[tm], 0, 0, 0);
        }
        size_t off = ((((size_t)rb * TT + t0 + t) * 4 + w) * 64 + L) * 16;
        uint4 lo, hi;
        lo.x = pk2(acc[0][0], acc[0][1]); lo.y = pk2(acc[0][2], acc[0][3]);
        lo.z = pk2(acc[1][0], acc[1][1]); lo.w = pk2(acc[1][2], acc[1][3]);
        hi.x = pk2(acc[2][0], acc[2][1]); hi.y = pk2(acc[2][2], acc[2][3]);
        hi.z = pk2(acc[3][0], acc[3][1]); hi.w = pk2(acc[3][2], acc[3][3]);
        *(uint4*)&xg[off] = lo;
        *(uint4*)&xg[off + 8] = hi;
    }
}

// ======================= PASS 2 (fused recurrence + heads) ================
// 64 blocks (16 rows each) x 4 waves. Wave w owns gate tiles {w,4+w,8+w,12+w}
// => lane holds i,f,g,o for units 16w+4q+jj of row n: shuffle-free update.
// xg prefetched in 8-step register chunks (one vmcnt drain per chunk).
// Heads computed in-loop (for time t-1 from the hb frag), flushed per chunk.
__global__ __launch_bounds__(256, 1)
void pass2_kernel(const unsigned short* __restrict__ xg,
                  const float* __restrict__ h0, const float* __restrict__ c0,
                  const float* __restrict__ W_hh,
                  const float* __restrict__ W_pred, const float* __restrict__ b_pred,
                  const float* __restrict__ W_z, const float* __restrict__ b_z,
                  float* __restrict__ out_pred, float* __restrict__ out_z,
                  float* __restrict__ out_h, float* __restrict__ out_c)
{
    __shared__ __attribute__((aligned(16))) unsigned short h_s[2][16 * 72];

    const int tid = threadIdx.x;
    const int w = tid >> 6, L = tid & 63, q = L >> 4, n = L & 15;
    const int rb = blockIdx.x;
    const int row = rb * 16 + n;
    const int m2b = 16 * w + 4 * q;   // head output rows this lane owns (m2b..m2b+3)

    // W_hh A-frags
    Frag ahh[4][2];
#pragma unroll
    for (int tm = 0; tm < 4; ++tm) {
        int m = 16 * (w + 4 * tm) + n;
#pragma unroll
        for (int kt = 0; kt < 2; ++kt)
#pragma unroll
            for (int j = 0; j < 8; ++j)
                ahh[tm][kt].u[j] = f2bf(W_hh[m * 64 + 32 * kt + 8 * q + j]);
    }
    // head A-frags: wave w owns combined-head M-tile w  (rows 16w..16w+15 of [pred;z;pad])
    Frag ahd[2];
    {
        int m = 16 * w + n;
#pragma unroll
        for (int kt = 0; kt < 2; ++kt)
#pragma unroll
            for (int j = 0; j < 8; ++j) {
                int k = 32 * kt + 8 * q + j;
                unsigned short v = 0;
                if (m < 18)      v = f2bf(W_pred[m * 64 + k]);
                else if (m < 50) v = f2bf(W_z[(m - 18) * 64 + k]);
                ahd[kt].u[j] = v;
            }
    }
    float bhd[4];
#pragma unroll
    for (int jj = 0; jj < 4; ++jj) {
        int m2 = m2b + jj;
        bhd[jj] = (m2 < 18) ? b_pred[m2] : (m2 < 50 ? b_z[m2 - 18] : 0.f);
    }

    // c state: lane owns units u = 16w+4q+jj of row n
    float c[4];
    {
        float4 cv = *(const float4*)&c0[(size_t)row * 64 + m2b];
        c[0] = cv.x; c[1] = cv.y; c[2] = cv.z; c[3] = cv.w;
    }
    // h init (cooperative): thread -> row tid>>4, units (tid&15)*4..+3
    {
        int r = tid >> 4, u0 = (tid & 15) * 4;
        float4 hv = *(const float4*)&h0[((size_t)(rb * 16 + r)) * 64 + u0];
        uint2 hw; hw.x = pk2(hv.x, hv.y); hw.y = pk2(hv.z, hv.w);
        *(uint2*)&h_s[0][r * 72 + u0] = hw;
    }
    __syncthreads();

    const unsigned short* xp = xg + (((size_t)rb * TT * 4 + w) * 64 + L) * 16;

    uint4 xbA[8][2], xbB[8][2];
    float hd[8][4];          // head results for times cb*8-1 .. cb*8+6
    float hout[4] = {0.f, 0.f, 0.f, 0.f};

    // preload chunk 0
#pragma unroll
    for (int s = 0; s < 8; ++s) {
        xbA[s][0] = *(const uint4*)(xp + (size_t)s * 4096);
        xbA[s][1] = *(const uint4*)(xp + (size_t)s * 4096 + 8);
    }

    auto chunk = [&](int cb, uint4 (&cur)[8][2], uint4 (&nxt)[8][2]) {
        // issue next chunk's loads (drained once, at this chunk's first barrier)
        if (cb + 1 < 128) {
#pragma unroll
            for (int s = 0; s < 8; ++s) {
                size_t o = ((size_t)((cb + 1) * 8 + s)) * 4096;
                nxt[s][0] = *(const uint4*)(xp + o);
                nxt[s][1] = *(const uint4*)(xp + o + 8);
            }
        }
#pragma unroll
        for (int ts = 0; ts < 8; ++ts) {
            const int p = ts & 1;           // cb*8 is even
            short8 hb0 = *(const short8*)&h_s[p][n * 72 + 8 * q];
            short8 hb1 = *(const short8*)&h_s[p][n * 72 + 32 + 8 * q];

            // head for time t-1 (hb holds h_{t-1})
            if (cb > 0 || ts > 0) {
                f32x4 ha = (f32x4){bhd[0], bhd[1], bhd[2], bhd[3]};
                ha = __builtin_amdgcn_mfma_f32_16x16x32_bf16(ahd[0].v, hb0, ha, 0, 0, 0);
                ha = __builtin_amdgcn_mfma_f32_16x16x32_bf16(ahd[1].v, hb1, ha, 0, 0, 0);
                hd[ts][0] = ha[0]; hd[ts][1] = ha[1]; hd[ts][2] = ha[2]; hd[ts][3] = ha[3];
            }

            // gates = xg + W_hh @ h
            uint4 lo = cur[ts][0], hi = cur[ts][1];
            f32x4 acc[4];
            acc[0] = (f32x4){bf2f(lo.x & 0xffff), bf2f(lo.x >> 16), bf2f(lo.y & 0xffff), bf2f(lo.y >> 16)};
            acc[1] = (f32x4){bf2f(lo.z & 0xffff), bf2f(lo.z >> 16), bf2f(lo.w & 0xffff), bf2f(lo.w >> 16)};
            acc[2] = (f32x4){bf2f(hi.x & 0xffff), bf2f(hi.x >> 16), bf2f(hi.y & 0xffff), bf2f(hi.y >> 16)};
            acc[3] = (f32x4){bf2f(hi.z & 0xffff), bf2f(hi.z >> 16), bf2f(hi.w & 0xffff), bf2f(hi.w >> 16)};
#pragma unroll
            for (int tm = 0; tm < 4; ++tm) {
                acc[tm] = __builtin_amdgcn_mfma_f32_16x16x32_bf16(ahh[tm][0].v, hb0, acc[tm], 0, 0, 0);
                acc[tm] = __builtin_amdgcn_mfma_f32_16x16x32_bf16(ahh[tm][1].v, hb1, acc[tm], 0, 0, 0);
            }
            // activations: acc[0]=i, acc[1]=f, acc[2]=g, acc[3]=o
#pragma unroll
            for (int jj = 0; jj < 4; ++jj) {
                float cn = sigm(acc[1][jj]) * c[jj] + sigm(acc[0][jj]) * tanh_(acc[2][jj]);
                c[jj] = cn;
                hout[jj] = sigm(acc[3][jj]) * tanh_(cn);
            }
            uint2 hw; hw.x = pk2(hout[0], hout[1]); hw.y = pk2(hout[2], hout[3]);
            *(uint2*)&h_s[1 - p][n * 72 + m2b] = hw;
            __syncthreads();
        }
        // flush heads for times cb*8-1 .. cb*8+6 (drained at next chunk's 1st barrier)
        if (m2b < 50) {
#pragma unroll
            for (int ts = 0; ts < 8; ++ts) {
                int tt_h = cb * 8 - 1 + ts;
                if (tt_h < 0) continue;
#pragma unroll
                for (int jj = 0; jj < 4; ++jj) {
                    int m2 = m2b + jj;
                    if (m2 < 18)
                        out_pred[((size_t)row * TT + tt_h) * NOBS + m2] = sigm(hd[ts][jj]);
                    else if (m2 < 50)
                        out_z[((size_t)row * TT + tt_h) * ZZ + (m2 - 18)] = hd[ts][jj];
                }
            }
        }
    };

    for (int cb2 = 0; cb2 < 64; ++cb2) {
        chunk(2 * cb2,     xbA, xbB);
        chunk(2 * cb2 + 1, xbB, xbA);
    }

    // head for final time t = TT-1 (h_1023 is in h_s[0] after the last step)
    {
        short8 hb0 = *(const short8*)&h_s[0][n * 72 + 8 * q];
        short8 hb1 = *(const short8*)&h_s[0][n * 72 + 32 + 8 * q];
        f32x4 ha = (f32x4){bhd[0], bhd[1], bhd[2], bhd[3]};
        ha = __builtin_amdgcn_mfma_f32_16x16x32_bf16(ahd[0].v, hb0, ha, 0, 0, 0);
        ha = __builtin_amdgcn_mfma_f32_16x16x32_bf16(ahd[1].v, hb1, ha, 0, 0, 0);
#pragma unroll
        for (int jj = 0; jj < 4; ++jj) {
            int m2 = m2b + jj;
            if (m2 < 18)
                out_pred[((size_t)row * TT + (TT - 1)) * NOBS + m2] = sigm(ha[jj]);
            else if (m2 < 50)
                out_z[((size_t)row * TT + (TT - 1)) * ZZ + (m2 - 18)] = ha[jj];
        }
    }
    // final state out (fp32)
    {
        size_t o = (size_t)row * 64 + m2b;
        *(float4*)&out_h[o] = make_float4(hout[0], hout[1], hout[2], hout[3]);
        *(float4*)&out_c[o] = make_float4(c[0], c[1], c[2], c[3]);
    }
}

// ===================== FALLBACK (R1 monolithic kernel) ====================
#define G4 256
#define RPB 2
__device__ __forceinline__ float tanh_safe(float x) {
    float ax = fabsf(x);
    float e = __expf(2.f * ax);
    float r = 1.f - 2.f / (e + 1.f);
    return copysignf(r, x);
}
__global__ __launch_bounds__(256, 2)
void wm_fallback(const float* __restrict__ obs, const float* __restrict__ act,
                 const float* __restrict__ h0, const float* __restrict__ c0,
                 const float* __restrict__ W_enc, const float* __restrict__ b_enc,
                 const float* __restrict__ W_ih, const float* __restrict__ W_hh,
                 const float* __restrict__ b_ih, const float* __restrict__ b_hh,
                 const float* __restrict__ W_pred, const float* __restrict__ b_pred,
                 const float* __restrict__ W_z, const float* __restrict__ b_z,
                 float* __restrict__ out_pred, float* __restrict__ out_z,
                 float* __restrict__ out_h, float* __restrict__ out_c)
{
    __shared__ __attribute__((aligned(16))) float wencT[23 * HH];
    __shared__ __attribute__((aligned(16))) float xs[RPB * HH];
    __shared__ __attribute__((aligned(16))) float hs[RPB * HH];
    __shared__ __attribute__((aligned(16))) float gbuf[RPB * G4];
    const int tid = threadIdx.x, bid = blockIdx.x;
    const int u = tid & 63, r = (tid >> 6) & 1;
    const bool lo = (tid < 128);
    const int rowg = bid * RPB + r;
    for (int i = tid; i < 23 * HH; i += 256) { int k = i >> 6, uu = i & 63; wencT[i] = W_enc[uu * 23 + k]; }
    float wih[HH], whh[HH];
    {
        const float4* pih = (const float4*)(W_ih + tid * HH);
        const float4* phh = (const float4*)(W_hh + tid * HH);
#pragma unroll
        for (int kk = 0; kk < 16; ++kk) {
            float4 a = pih[kk]; wih[4*kk] = a.x; wih[4*kk+1] = a.y; wih[4*kk+2] = a.z; wih[4*kk+3] = a.w;
            float4 b = phh[kk]; whh[4*kk] = b.x; whh[4*kk+1] = b.y; whh[4*kk+2] = b.z; whh[4*kk+3] = b.w;
        }
    }
    const float bias = b_ih[tid] + b_hh[tid];
    const float benc = b_enc[u];
    float wout[HH]; float bout = 0.f;
    {
        const float* src;
        if (u < 18) { src = W_pred + u * HH; bout = b_pred[u]; }
        else if (u < 50) { src = W_z + (u - 18) * HH; bout = b_z[u - 18]; }
        else src = W_pred;
        const float4* p4 = (const float4*)src;
#pragma unroll
        for (int kk = 0; kk < 16; ++kk) { float4 a = p4[kk]; wout[4*kk] = a.x; wout[4*kk+1] = a.y; wout[4*kk+2] = a.z; wout[4*kk+3] = a.w; }
    }
    float c = 0.f;
    if (lo) { hs[r * HH + u] = h0[(size_t)rowg * HH + u]; c = c0[(size_t)rowg * HH + u]; }
    const float* obs_row = obs + (size_t)rowg * TT * NOBS;
    const float* act_row = act + (size_t)rowg * TT * NACT;
    float* outp_row = out_pred + (size_t)rowg * TT * NOBS;
    float* outz_row = out_z + (size_t)rowg * TT * ZZ;
    __syncthreads();
    for (int t = 0; t < TT; ++t) {
        if (lo) {
            const float* op = obs_row + t * NOBS; const float* ap = act_row + t * NACT;
            float a = benc;
#pragma unroll
            for (int k = 0; k < NOBS; ++k) a = fmaf(op[k], wencT[k * HH + u], a);
#pragma unroll
            for (int k = 0; k < NACT; ++k) a = fmaf(ap[k], wencT[(NOBS + k) * HH + u], a);
            xs[r * HH + u] = fmaxf(a, 0.f);
        }
        __syncthreads();
        {
            float a0 = bias, b0 = 0.f, a1 = bias, b1 = 0.f;
            const float4* x4 = (const float4*)xs; const float4* h4 = (const float4*)hs;
#pragma unroll
            for (int kk = 0; kk < 16; ++kk) {
                float4 xv0 = x4[kk], hv0 = h4[kk], xv1 = x4[16 + kk], hv1 = h4[16 + kk];
                a0 = fmaf(wih[4*kk], xv0.x, a0); a0 = fmaf(wih[4*kk+1], xv0.y, a0);
                a0 = fmaf(wih[4*kk+2], xv0.z, a0); a0 = fmaf(wih[4*kk+3], xv0.w, a0);
                b0 = fmaf(whh[4*kk], hv0.x, b0); b0 = fmaf(whh[4*kk+1], hv0.y, b0);
                b0 = fmaf(whh[4*kk+2], hv0.z, b0); b0 = fmaf(whh[4*kk+3], hv0.w, b0);
                a1 = fmaf(wih[4*kk], xv1.x, a1); a1 = fmaf(wih[4*kk+1], xv1.y, a1);
                a1 = fmaf(wih[4*kk+2], xv1.z, a1); a1 = fmaf(wih[4*kk+3], xv1.w, a1);
                b1 = fmaf(whh[4*kk], hv1.x, b1); b1 = fmaf(whh[4*kk+1], hv1.y, b1);
                b1 = fmaf(whh[4*kk+2], hv1.z, b1); b1 = fmaf(whh[4*kk+3], hv1.w, b1);
            }
            gbuf[tid] = a0 + b0; gbuf[G4 + tid] = a1 + b1;
        }
        __syncthreads();
        if (lo) {
            float gi = gbuf[r * G4 + u], gf = gbuf[r * G4 + 64 + u];
            float gg = gbuf[r * G4 + 128 + u], go = gbuf[r * G4 + 192 + u];
            c = sigm(gf) * c + sigm(gi) * tanh_safe(gg);
            float ht = sigm(go) * tanh_safe(c);
            hs[r * HH + u] = ht;
            if (t == TT - 1) { out_h[(size_t)rowg * HH + u] = ht; out_c[(size_t)rowg * HH + u] = c; }
        }
        __syncthreads();
        if (!lo && u < 50) {
            float a = bout;
            const float4* h4 = (const float4*)(hs + r * HH);
#pragma unroll
            for (int kk = 0; kk < 16; ++kk) {
                float4 hv = h4[kk];
                a = fmaf(wout[4*kk], hv.x, a); a = fmaf(wout[4*kk+1], hv.y, a);
                a = fmaf(wout[4*kk+2], hv.z, a); a = fmaf(wout[4*kk+3], hv.w, a);
            }
            if (u < 18) outp_row[t * NOBS + u] = sigm(a);
            else outz_row[t * ZZ + (u - 18)] = a;
        }
    }
}

// ============================ LAUNCH =====================================
extern "C" void kernel_launch(void* const* d_in, const int* in_sizes, int n_in,
                              void* d_out, int out_size, void* d_ws, size_t ws_size,
                              hipStream_t stream)
{
    const float* obs    = (const float*)d_in[0];
    const float* act    = (const float*)d_in[1];
    const float* h0     = (const float*)d_in[2];
    const float* c0     = (const float*)d_in[3];
    const float* W_enc  = (const float*)d_in[4];
    const float* b_enc  = (const float*)d_in[5];
    const float* W_ih   = (const float*)d_in[6];
    const float* W_hh   = (const float*)d_in[7];
    const float* b_ih   = (const float*)d_in[8];
    const float* b_hh   = (const float*)d_in[9];
    const float* W_pred = (const float*)d_in[10];
    const float* b_pred = (const float*)d_in[11];
    const float* W_z    = (const float*)d_in[12];
    const float* b_z    = (const float*)d_in[13];

    float* out      = (float*)d_out;
    float* out_pred = out;
    float* out_z    = out_pred + (size_t)BB * TT * NOBS;
    float* out_h    = out_z + (size_t)BB * TT * ZZ;
    float* out_c    = out_h + (size_t)BB * HH;

    if (ws_size >= WS_NEEDED) {
        unsigned short* xg = (unsigned short*)d_ws;
        pass1_kernel<<<dim3(64 * 64), dim3(256), 0, stream>>>(
            obs, act, W_enc, b_enc, W_ih, b_ih, b_hh, xg);
        pass2_kernel<<<dim3(64), dim3(256), 0, stream>>>(
            xg, h0, c0, W_hh, W_pred, b_pred, W_z, b_z,
            out_pred, out_z, out_h, out_c);
    } else {
        wm_fallback<<<dim3(BB / RPB), dim3(256), 0, stream>>>(
            obs, act, h0, c0, W_enc, b_enc, W_ih, W_hh, b_ih, b_hh,
            W_pred, b_pred, W_z, b_z, out_pred, out_z, out_h, out_c);
    }
}